// Round 11
// baseline (7130.950 us; speedup 1.0000x reference)
//
#include <hip/hip_runtime.h>
#include <cstdint>
#include <cstddef>

typedef unsigned short u16;

#define B_  2
#define S_  2048
#define D_  2048
#define H_  16
#define HD_ 128

__device__ __forceinline__ float bf2f(u16 v) { return __uint_as_float(((unsigned)v) << 16); }
__device__ __forceinline__ u16 f2bf(float f) {
    unsigned u = __float_as_uint(f);
    return (u16)((u + 0x7fffu + ((u >> 16) & 1u)) >> 16);
}
__device__ __forceinline__ float ldf(const void* p, size_t i, int m) {
    return m ? ((const float*)p)[i] : bf2f(((const u16*)p)[i]);
}

// ---------------- dtype flag ----------------
__global__ void k_flag(const unsigned* __restrict__ gw, int* __restrict__ mode) {
    if (threadIdx.x == 0 && blockIdx.x == 0) *mode = (gw[0] == 0x3F803F80u) ? 0 : 1;
}

// ---------------- RMSNorm (exact reference epsilons) ----------------
__global__ __launch_bounds__(256) void k_rmsnorm(const void* __restrict__ x,
                                                 const void* __restrict__ g,
                                                 const int* __restrict__ mode,
                                                 u16* __restrict__ xn) {
    int m = *mode;
    int row = blockIdx.x;
    int t = threadIdx.x;
    float v[8];
    if (m) {
        const float* xr = (const float*)x + (size_t)row * D_;
        float4 a = ((const float4*)xr)[t * 2], b2 = ((const float4*)xr)[t * 2 + 1];
        v[0] = a.x; v[1] = a.y; v[2] = a.z; v[3] = a.w;
        v[4] = b2.x; v[5] = b2.y; v[6] = b2.z; v[7] = b2.w;
    } else {
        const u16* xr = (const u16*)x + (size_t)row * D_;
        uint4 w = *(const uint4*)(xr + t * 8);
        const u16* pw = (const u16*)&w;
#pragma unroll
        for (int i = 0; i < 8; i++) v[i] = bf2f(pw[i]);
    }
    float s = 0.f;
#pragma unroll
    for (int i = 0; i < 8; i++) {
        v[i] += 1e-6f;                     // xa = x + EPS
        float q = v[i] + 1e-6f;            // (xa + EPS)^2
        s += q * q;
    }
    for (int off = 1; off < 64; off <<= 1) s += __shfl_xor(s, off, 64);
    __shared__ float red[4];
    int wv = t >> 6, ln = t & 63;
    if (ln == 0) red[wv] = s;
    __syncthreads();
    s = red[0] + red[1] + red[2] + red[3];
    float n = sqrtf(s) * 45.254833995939045f;   // sqrt(2048)
    float inv = 1.0f / (n + 1e-6f);
    u16* outr = xn + (size_t)row * D_;
    u16 o[8];
#pragma unroll
    for (int i = 0; i < 8; i++) o[i] = f2bf(v[i] * inv * ldf(g, t * 8 + i, m));
    *(uint4*)(outr + t * 8) = *(const uint4*)o;
}

// ---------------- VALU GEMM: out[n] = sum_k A[k] * W[k*D+n] + bias[n] ----------------
// scatter=1: bf16 scatter to (B,H,S,HD). scatter=0: f32 write to dstf[gm*D+n].
__global__ __launch_bounds__(256)
void k_gemm_valu(const u16* __restrict__ A, const void* __restrict__ W,
                 const void* __restrict__ bias, const int* __restrict__ mode,
                 u16* __restrict__ dstb, float* __restrict__ dstf, int scatter) {
    int m_ = *mode;
    int n = blockIdx.x * 64 + (threadIdx.x & 63);
    int mrow0 = blockIdx.y * 32 + (threadIdx.x >> 6) * 8;
    float acc[8] = {0.f, 0.f, 0.f, 0.f, 0.f, 0.f, 0.f, 0.f};
    for (int k0 = 0; k0 < D_; k0 += 8) {
        float wv8[8];
#pragma unroll
        for (int t = 0; t < 8; t++) wv8[t] = ldf(W, (size_t)(k0 + t) * D_ + n, m_);
#pragma unroll
        for (int j = 0; j < 8; j++) {
            uint4 a4 = *(const uint4*)(A + (size_t)(mrow0 + j) * D_ + k0);
            const u16* ap = (const u16*)&a4;
#pragma unroll
            for (int t = 0; t < 8; t++) acc[j] += bf2f(ap[t]) * wv8[t];
        }
    }
    float bs = ldf(bias, n, m_);
#pragma unroll
    for (int j = 0; j < 8; j++) {
        int gm = mrow0 + j;
        float val = acc[j] + bs;
        if (!scatter) {
            dstf[(size_t)gm * D_ + n] = val;          // f32 output (harness reads f32!)
        } else {
            int hh = n >> 7, d = n & 127;
            int b = gm >> 11, s = gm & 2047;
            dstb[((size_t)((b << 4) + hh) * S_ + s) * HD_ + d] = f2bf(val);
        }
    }
}

// ---------------- RoPE ----------------
__global__ void k_rope(u16* __restrict__ Q, u16* __restrict__ K, const int* __restrict__ pos) {
    int idx = blockIdx.x;
    int s = idx & (S_ - 1);
    int i = threadIdx.x;
    float p = (float)pos[s];
    float inv_freq = expf(-((float)(2 * i) * (1.0f / 128.0f)) * 13.122363377404328f);
    float f = p * inv_freq;
    float sn = sinf(f), c = cosf(f);
    size_t base = (size_t)idx * HD_;
    float a = bf2f(Q[base + i]), b = bf2f(Q[base + i + 64]);
    Q[base + i] = f2bf(a * c - b * sn);
    Q[base + i + 64] = f2bf(b * c + a * sn);
    a = bf2f(K[base + i]); b = bf2f(K[base + i + 64]);
    K[base + i] = f2bf(a * c - b * sn);
    K[base + i + 64] = f2bf(b * c + a * sn);
}

// ---------------- lambda ----------------
__global__ void k_lambda(const void* lq1, const void* lk1, const void* lq2, const void* lk2,
                         const void* linit, const int* __restrict__ mode, float* lam) {
    int m = *mode;
    int h = blockIdx.x;
    int d = threadIdx.x;
    float p1 = ldf(lq1, h * 128 + d, m) * ldf(lk1, h * 128 + d, m);
    float p2 = ldf(lq2, h * 128 + d, m) * ldf(lk2, h * 128 + d, m);
    for (int off = 1; off < 64; off <<= 1) { p1 += __shfl_xor(p1, off, 64); p2 += __shfl_xor(p2, off, 64); }
    __shared__ float r1[2], r2[2];
    int wv = d >> 6, ln = d & 63;
    if (ln == 0) { r1[wv] = p1; r2[wv] = p2; }
    __syncthreads();
    if (d == 0) {
        float L = expf(r1[0] + r1[1]) - expf(r2[0] + r2[1]) + ldf(linit, h, m);
        lam[h] = fminf(fmaxf(L, 0.f), 1.f);
    }
}

// ---------------- VALU causal flash attention ----------------
__global__ __launch_bounds__(256, 2)
void k_fattn_valu(const u16* __restrict__ Q, const u16* __restrict__ K,
                  const u16* __restrict__ V, float* __restrict__ O) {
    __shared__ u16 Kt[64 * 136];
    __shared__ u16 Vt[64 * 136];
    int bh = blockIdx.y, q0 = blockIdx.x * 64;
    const u16* Qh = Q + (size_t)bh * S_ * HD_;
    const u16* Kh = K + (size_t)bh * S_ * HD_;
    const u16* Vh = V + (size_t)bh * S_ * HD_;
    float* Oh = O + (size_t)bh * S_ * HD_;
    int tid = threadIdx.x;
    int row = tid >> 2, part = tid & 3;
    int qr = q0 + row;
    float q[32], o[32];
    const u16* qp = Qh + (size_t)qr * HD_ + part * 32;
#pragma unroll
    for (int i = 0; i < 32; i++) { q[i] = bf2f(qp[i]); o[i] = 0.f; }
    float m = -3e38f, l = 0.f;
    const float scale = 0.08838834764831845f;
    int kb_end = q0 >> 6;
    for (int kb = 0; kb <= kb_end; kb++) {
        __syncthreads();
#pragma unroll
        for (int p = 0; p < 4; p++) {
            int ci = p * 256 + tid;
            int r2 = ci >> 4, c = (ci & 15) * 8;
            *(uint4*)&Kt[r2 * 136 + c] = *(const uint4*)(Kh + (size_t)(kb * 64 + r2) * HD_ + c);
            *(uint4*)&Vt[r2 * 136 + c] = *(const uint4*)(Vh + (size_t)(kb * 64 + r2) * HD_ + c);
        }
        __syncthreads();
        int jmax = qr - kb * 64;
        if (jmax > 63) jmax = 63;
        for (int j = 0; j <= jmax; j++) {
            const u16* kr = &Kt[j * 136 + part * 32];
            float s = 0.f;
#pragma unroll
            for (int i = 0; i < 32; i++) s += q[i] * bf2f(kr[i]);
            s += __shfl_xor(s, 1, 64);
            s += __shfl_xor(s, 2, 64);
            s *= scale;
            float mn = fmaxf(m, s);
            float alpha = __expf(m - mn);
            float pj = __expf(s - mn);
            m = mn;
            l = l * alpha + pj;
            const u16* vr = &Vt[j * 136 + part * 32];
#pragma unroll
            for (int i = 0; i < 32; i++) o[i] = o[i] * alpha + pj * bf2f(vr[i]);
        }
    }
    float inv = 1.0f / l;
    float* op = Oh + (size_t)qr * HD_ + part * 32;
#pragma unroll
    for (int i = 0; i < 32; i++) op[i] = o[i] * inv;
}

// ---------------- combine + headnorm ----------------
__global__ __launch_bounds__(128)
void k_combine(const float* __restrict__ O, const float* __restrict__ lam,
               const void* __restrict__ gamma, const void* __restrict__ beta,
               const int* __restrict__ mode, u16* __restrict__ XA) {
    int m = *mode;
    int idx = blockIdx.x;
    int s = idx & (S_ - 1);
    int bh8 = idx >> 11;
    int h8 = bh8 & 7, b = bh8 >> 3;
    const float* o1 = O + ((size_t)((b << 4) + h8) * S_ + s) * HD_;
    const float* o2 = O + ((size_t)((b << 4) + h8 + 8) * S_ + s) * HD_;
    int d = threadIdx.x;
    float u = o1[d] - lam[h8] * o2[d];
    float su = u, sq = u * u;
    for (int off = 1; off < 64; off <<= 1) { su += __shfl_xor(su, off, 64); sq += __shfl_xor(sq, off, 64); }
    __shared__ float red[4];
    int wv = d >> 6, ln = d & 63;
    if (ln == 0) { red[wv * 2] = su; red[wv * 2 + 1] = sq; }
    __syncthreads();
    su = red[0] + red[2]; sq = red[1] + red[3];
    float mean = su * (1.0f / 128.0f);
    float var = fmaxf(sq * (1.0f / 128.0f) - mean * mean, 0.f);
    float inv = 1.0f / sqrtf(var + 1e-5f);
    float un = (u - mean) * inv;
    u16* xr = XA + (size_t)(b * S_ + s) * D_;
    xr[h8 * 128 + d] = f2bf(ldf(gamma, h8, m) * un + ldf(beta, h8, m));
    xr[(h8 + 8) * 128 + d] = f2bf(ldf(gamma, h8 + 8, m) * un + ldf(beta, h8 + 8, m));
}

extern "C" void kernel_launch(void* const* d_in, const int* in_sizes, int n_in,
                              void* d_out, int out_size, void* d_ws, size_t ws_size,
                              hipStream_t stream) {
    const void* x = d_in[0];
    const int* pos = (const int*)d_in[1];
    const void* wq = d_in[2];
    const void* bq = d_in[3];
    const void* wk = d_in[4];
    const void* bk = d_in[5];
    const void* wv = d_in[6];
    const void* bv = d_in[7];
    const void* wo = d_in[8];
    const void* bo = d_in[9];
    const void* g = d_in[10];
    const void* gamma = d_in[11];
    const void* beta = d_in[12];
    const void* linit = d_in[13];
    const void* lq1 = d_in[14];
    const void* lk1 = d_in[15];
    const void* lq2 = d_in[16];
    const void* lk2 = d_in[17];
    (void)in_sizes; (void)n_in; (void)out_size;

    u16* XN = (u16*)d_ws;
    u16* Qb = XN + (size_t)B_ * S_ * D_;
    u16* Kb = Qb + (size_t)B_ * S_ * D_;
    u16* Vb = Kb + (size_t)B_ * S_ * D_;
    float* LAM = (float*)(Vb + (size_t)B_ * S_ * D_);
    float* Ob = LAM + 64;
    u16* XA = (u16*)(Ob + (size_t)B_ * H_ * S_ * HD_);
    int* MODE = (int*)(XA + (size_t)B_ * S_ * D_);
    size_t need = (size_t)((char*)(MODE + 16) - (char*)d_ws);
    if (ws_size < need) return;

    dim3 ggrid(D_ / 64, (B_ * S_) / 32);
    k_flag<<<1, 64, 0, stream>>>((const unsigned*)g, MODE);
    k_rmsnorm<<<B_ * S_, 256, 0, stream>>>(x, g, MODE, XN);
    k_gemm_valu<<<ggrid, 256, 0, stream>>>(XN, wq, bq, MODE, Qb, nullptr, 1);
    k_gemm_valu<<<ggrid, 256, 0, stream>>>(XN, wk, bk, MODE, Kb, nullptr, 1);
    k_gemm_valu<<<ggrid, 256, 0, stream>>>(XN, wv, bv, MODE, Vb, nullptr, 1);
    k_rope<<<B_ * H_ * S_, 64, 0, stream>>>(Qb, Kb, pos);
    k_lambda<<<8, 128, 0, stream>>>(lq1, lk1, lq2, lk2, linit, MODE, LAM);
    k_fattn_valu<<<dim3(S_ / 64, B_ * H_), 256, 0, stream>>>(Qb, Kb, Vb, Ob);
    k_combine<<<B_ * 8 * S_, 128, 0, stream>>>(Ob, LAM, gamma, beta, MODE, XA);
    k_gemm_valu<<<ggrid, 256, 0, stream>>>(XA, wo, bo, MODE, nullptr, (float*)d_out, 0);
}